// Round 1
// baseline (2957.045 us; speedup 1.0000x reference)
//
#include <hip/hip_runtime.h>

typedef __attribute__((ext_vector_type(8))) short short8;
typedef __attribute__((ext_vector_type(4))) float f32x4;

#define CDIM 512
#define NSEQ 16384

__device__ __forceinline__ unsigned short f2bf(float f) {
    unsigned u = __float_as_uint(f);
    unsigned r = ((u >> 16) & 1u) + 0x7fffu;
    return (unsigned short)((u + r) >> 16);
}

// ---------------------------------------------------------------------------
// Build augmented G = [I + A | I - A], A = W - W^T.  G: 512 rows x 1024 cols.
// ---------------------------------------------------------------------------
__global__ void buildG_kernel(const float* __restrict__ W, float* __restrict__ G) {
    int r = blockIdx.x;
    for (int c = threadIdx.x; c < 1024; c += 256) {
        float v;
        if (c < 512) {
            float a = W[r * 512 + c] - W[c * 512 + r];
            v = (c == r ? 1.f : 0.f) + a;
        } else {
            int c2 = c - 512;
            float a = W[r * 512 + c2] - W[c2 * 512 + r];
            v = (c2 == r ? 1.f : 0.f) - a;
        }
        G[(size_t)r * 1024 + c] = v;
    }
}

// ---------------------------------------------------------------------------
// Invert 128x128 diagonal block via register-resident Gauss-Jordan.
// 512 threads: c0 = t&63 (cols c0+64q, q=0..3 over augmented width 256),
//              rg = t>>6 (rows rg+8m, m=0..15).  No pivoting (pivots >= 1).
// ---------------------------------------------------------------------------
__global__ __launch_bounds__(512) void invdiag_kernel(float* __restrict__ G,
                                                      float* __restrict__ Dinv, int k) {
    int ck = k * 128;
    __shared__ float prow[2][256];
    __shared__ float pcol[2][128];
    int t = threadIdx.x;
    int c0 = t & 63, rg = t >> 6;
    float rgs[16][4];
#pragma unroll
    for (int m = 0; m < 16; m++) {
        int r = rg + 8 * m;
#pragma unroll
        for (int q = 0; q < 4; q++) {
            int c = c0 + 64 * q;
            rgs[m][q] = (c < 128) ? G[(size_t)(ck + r) * 1024 + ck + c]
                                  : ((r == c - 128) ? 1.f : 0.f);
        }
    }
    // publish pivot 0 into buffer 0
    if (rg == 0) {
#pragma unroll
        for (int q = 0; q < 4; q++) prow[0][c0 + 64 * q] = rgs[0][q];
    }
    if (c0 == 0) {
#pragma unroll
        for (int m = 0; m < 16; m++) pcol[0][rg + 8 * m] = rgs[m][0];
    }
    __syncthreads();
    for (int p = 0; p < 128; p++) {
        int buf = p & 1;
        float inv = 1.0f / prow[buf][p];
        float pr[4];
#pragma unroll
        for (int q = 0; q < 4; q++) pr[q] = prow[buf][c0 + 64 * q];
#pragma unroll
        for (int m = 0; m < 16; m++) {
            int r = rg + 8 * m;
            if (r == p) {  // wave-uniform branch (rg is wave-uniform)
#pragma unroll
                for (int q = 0; q < 4; q++) rgs[m][q] = pr[q] * inv;
            } else {
                float f = pcol[buf][r] * inv;
#pragma unroll
                for (int q = 0; q < 4; q++) rgs[m][q] -= f * pr[q];
            }
        }
        if (p < 127) {
            int p2 = p + 1, nb = p2 & 1;
            int mp = p2 >> 3, qp = p2 >> 6;
            if (rg == (p2 & 7)) {
#pragma unroll
                for (int m = 0; m < 16; m++)
                    if (m == mp) {
#pragma unroll
                        for (int q = 0; q < 4; q++) prow[nb][c0 + 64 * q] = rgs[m][q];
                    }
            }
            if (c0 == (p2 & 63)) {
#pragma unroll
                for (int q = 0; q < 4; q++)
                    if (q == qp) {
#pragma unroll
                        for (int m = 0; m < 16; m++) pcol[nb][rg + 8 * m] = rgs[m][q];
                    }
            }
        }
        __syncthreads();
    }
    // right half of augmented block = Dinv
#pragma unroll
    for (int m = 0; m < 16; m++) {
        Dinv[(rg + 8 * m) * 128 + c0] = rgs[m][2];
        Dinv[(rg + 8 * m) * 128 + c0 + 64] = rgs[m][3];
    }
}

// ---------------------------------------------------------------------------
// Pivot block-row scale: G[Rk, cbase:cbase+64] = Dinv x G[Rk, cbase:cbase+64]
// Active cols are [ck+128, 1024), contiguous.  grid.x = (896-128k)/64.
// ---------------------------------------------------------------------------
__global__ void rowscale_kernel(float* __restrict__ G, const float* __restrict__ Dinv,
                                int k) {
    int ck = k * 128;
    int cbase = ck + 128 + blockIdx.x * 64;
    __shared__ float ins[128][64];
    __shared__ float dch[128][33];
    int t = threadIdx.x;
    for (int idx = t; idx < 128 * 64; idx += 256) {
        int r = idx >> 6, c = idx & 63;
        ins[r][c] = G[(size_t)(ck + r) * 1024 + cbase + c];
    }
    int tx = t & 15, ty = t >> 4;
    float acc[8][4];
#pragma unroll
    for (int i = 0; i < 8; i++)
#pragma unroll
        for (int j = 0; j < 4; j++) acc[i][j] = 0.f;
    for (int mc = 0; mc < 4; mc++) {
        __syncthreads();
        for (int idx = t; idx < 128 * 32; idx += 256) {
            int r = idx >> 5, c = idx & 31;
            dch[r][c] = Dinv[r * 128 + mc * 32 + c];
        }
        __syncthreads();
        for (int m2 = 0; m2 < 32; m2++) {
            int mm = mc * 32 + m2;
            float p0 = ins[mm][tx * 4 + 0], p1 = ins[mm][tx * 4 + 1];
            float p2 = ins[mm][tx * 4 + 2], p3 = ins[mm][tx * 4 + 3];
#pragma unroll
            for (int rr = 0; rr < 8; rr++) {
                float d = dch[ty * 8 + rr][m2];
                acc[rr][0] += d * p0;
                acc[rr][1] += d * p1;
                acc[rr][2] += d * p2;
                acc[rr][3] += d * p3;
            }
        }
    }
#pragma unroll
    for (int rr = 0; rr < 8; rr++)
#pragma unroll
        for (int cc = 0; cc < 4; cc++)
            G[(size_t)(ck + ty * 8 + rr) * 1024 + cbase + tx * 4 + cc] = acc[rr][cc];
}

// ---------------------------------------------------------------------------
// Trailing update: G[i, c] -= G[i, ck:ck+128] x G[Rk, c] for i not in Rk.
// grid = (12 row-tiles of 32, (896-128k)/64 col-tiles)
// ---------------------------------------------------------------------------
__global__ void trailing_kernel(float* __restrict__ G, int k) {
    int ck = k * 128;
    int rb = blockIdx.x * 32;
    if (rb >= ck) rb += 128;
    int cbase = ck + 128 + blockIdx.y * 64;
    __shared__ float Lt[32][129];
    __shared__ float Pt[128][64];
    int t = threadIdx.x;
    for (int idx = t; idx < 32 * 128; idx += 256) {
        int r = idx >> 7, c = idx & 127;
        Lt[r][c] = G[(size_t)(rb + r) * 1024 + ck + c];
    }
    for (int idx = t; idx < 128 * 64; idx += 256) {
        int r = idx >> 6, c = idx & 63;
        Pt[r][c] = G[(size_t)(ck + r) * 1024 + cbase + c];
    }
    __syncthreads();
    int tx = t & 15, ty = t >> 4;
    float acc[2][4];
#pragma unroll
    for (int i = 0; i < 2; i++)
#pragma unroll
        for (int j = 0; j < 4; j++) acc[i][j] = 0.f;
    for (int mm = 0; mm < 128; mm++) {
        float p0 = Pt[mm][tx * 4 + 0], p1 = Pt[mm][tx * 4 + 1];
        float p2 = Pt[mm][tx * 4 + 2], p3 = Pt[mm][tx * 4 + 3];
        float l0 = Lt[ty * 2 + 0][mm], l1 = Lt[ty * 2 + 1][mm];
        acc[0][0] += l0 * p0; acc[0][1] += l0 * p1; acc[0][2] += l0 * p2; acc[0][3] += l0 * p3;
        acc[1][0] += l1 * p0; acc[1][1] += l1 * p1; acc[1][2] += l1 * p2; acc[1][3] += l1 * p3;
    }
#pragma unroll
    for (int rr = 0; rr < 2; rr++)
#pragma unroll
        for (int cc = 0; cc < 4; cc++)
            G[(size_t)(rb + ty * 2 + rr) * 1024 + cbase + tx * 4 + cc] -= acc[rr][cc];
}

// ---------------------------------------------------------------------------
// Convert K (= right half of G) to bf16, row-major 512x512.
// ---------------------------------------------------------------------------
__global__ void cvtK_kernel(const float* __restrict__ G, unsigned short* __restrict__ Kb) {
    int idx = blockIdx.x * 256 + threadIdx.x;  // 65536 threads x 4 elems
    int e = idx * 4;
    int j = e >> 9, i = e & 511;
    const float* src = G + (size_t)j * 1024 + 512 + i;
    unsigned short* dst = Kb + j * 512 + i;
    float v0 = src[0], v1 = src[1], v2 = src[2], v3 = src[3];
    unsigned p0 = f2bf(v0), p1 = f2bf(v1), p2 = f2bf(v2), p3 = f2bf(v3);
    uint2 pk;
    pk.x = p0 | (p1 << 16);
    pk.y = p2 | (p3 << 16);
    *(uint2*)dst = pk;
}

// ---------------------------------------------------------------------------
// Main GEMM: y[b, j, n] = sum_i K[j,i] x[b,i,n].  Block = all 512 j, 64 n.
// 512 threads = 8 waves; wave w owns j in [64w, 64w+64), mfma 16x16x32 bf16.
// ---------------------------------------------------------------------------
#define LDK 40  // padded row length (bf16 elems) -> 80 B, 16B-aligned rows

__global__ __launch_bounds__(512, 4) void gemm_kernel(const float* __restrict__ x,
                                                      const unsigned short* __restrict__ Kb,
                                                      float* __restrict__ y) {
    __shared__ unsigned short kt[512 * LDK];  // K tile: 512 j x 32 i (bf16)
    __shared__ unsigned short xt[64 * LDK];   // x tile: 64 n x 32 i (bf16)
    int t = threadIdx.x;
    int l = t & 63, w = t >> 6;
    int bx = blockIdx.x;
    int b = bx >> 8;
    int n0 = (bx & 255) << 6;
    const float* xb = x + (size_t)b * CDIM * NSEQ + n0;
    float* yb = y + (size_t)b * CDIM * NSEQ + n0;

    f32x4 acc[4][4];
#pragma unroll
    for (int i = 0; i < 4; i++)
#pragma unroll
        for (int j = 0; j < 4; j++) acc[i][j] = (f32x4){0.f, 0.f, 0.f, 0.f};

    int lr = l & 15;
    int q8 = (l >> 4) * 8;  // k-offset (elements) of this lane's fragment

    for (int s = 0; s < 16; s++) {
        __syncthreads();
        {  // stage K: thread t loads row j=t, 32 bf16 (64 B)
            const uint4* src = (const uint4*)(Kb + t * CDIM + s * 32);
            uint4* dst = (uint4*)(kt + t * LDK);
#pragma unroll
            for (int i = 0; i < 4; i++) dst[i] = src[i];
        }
        {  // stage x: wave w loads i = s*32 + 4w + r, n = n0 + l; cvt to bf16
            const float* xs = xb + (size_t)(s * 32 + w * 4) * NSEQ + l;
            unsigned p0 = f2bf(xs[0]);
            unsigned p1 = f2bf(xs[NSEQ]);
            unsigned p2 = f2bf(xs[2 * NSEQ]);
            unsigned p3 = f2bf(xs[3 * NSEQ]);
            uint2 pk;
            pk.x = p0 | (p1 << 16);
            pk.y = p2 | (p3 << 16);
            *(uint2*)(xt + l * LDK + w * 4) = pk;
        }
        __syncthreads();
        short8 af[4], bfr[4];
#pragma unroll
        for (int mt = 0; mt < 4; mt++)
            af[mt] = *(const short8*)(kt + (w * 64 + mt * 16 + lr) * LDK + q8);
#pragma unroll
        for (int nt = 0; nt < 4; nt++)
            bfr[nt] = *(const short8*)(xt + (nt * 16 + lr) * LDK + q8);
#pragma unroll
        for (int mt = 0; mt < 4; mt++)
#pragma unroll
            for (int nt = 0; nt < 4; nt++)
                acc[mt][nt] = __builtin_amdgcn_mfma_f32_16x16x32_bf16(af[mt], bfr[nt],
                                                                      acc[mt][nt], 0, 0, 0);
    }
    int qr = (l >> 4) * 4;
#pragma unroll
    for (int mt = 0; mt < 4; mt++)
#pragma unroll
        for (int nt = 0; nt < 4; nt++)
#pragma unroll
            for (int r = 0; r < 4; r++)
                yb[(size_t)(w * 64 + mt * 16 + qr + r) * NSEQ + nt * 16 + lr] =
                    acc[mt][nt][r];
}

// ---------------------------------------------------------------------------
extern "C" void kernel_launch(void* const* d_in, const int* in_sizes, int n_in,
                              void* d_out, int out_size, void* d_ws, size_t ws_size,
                              hipStream_t stream) {
    const float* x = (const float*)d_in[0];
    const float* W = (const float*)d_in[1];
    float* y = (float*)d_out;

    float* G = (float*)d_ws;                                        // 2 MB
    float* DINV = (float*)((char*)d_ws + 0x200000);                 // 64 KB
    unsigned short* KB = (unsigned short*)((char*)d_ws + 0x210000); // 512 KB

    buildG_kernel<<<512, 256, 0, stream>>>(W, G);
    for (int k = 0; k < 4; k++) {
        invdiag_kernel<<<1, 512, 0, stream>>>(G, DINV, k);
        int ncols = 896 - 128 * k;
        rowscale_kernel<<<ncols / 64, 256, 0, stream>>>(G, DINV, k);
        trailing_kernel<<<dim3(12, ncols / 64), 256, 0, stream>>>(G, k);
    }
    cvtK_kernel<<<256, 256, 0, stream>>>(G, KB);
    gemm_kernel<<<4096, 512, 0, stream>>>(x, KB, y);
}